// Round 13
// baseline (460.332 us; speedup 1.0000x reference)
//
#include <hip/hip_runtime.h>
#include <math.h>

#define N_NODES 50000
#define N_EDGES 200000
#define NEG_SLOPE 0.2f
#define BN_EPS 1e-5f

#define SCAN_ELEMS 1024
#define SCAN_NB ((N_NODES + SCAN_ELEMS - 1) / SCAN_ELEMS)  // 49

typedef __attribute__((ext_vector_type(4))) float f32x4;
typedef __attribute__((ext_vector_type(8))) short bf16x8;
typedef __attribute__((ext_vector_type(8))) ushort u16x8;
typedef __attribute__((ext_vector_type(2))) ushort u16x2;

__device__ __forceinline__ ushort f2bf(float x) {
    unsigned u = __float_as_uint(x);
    u += 0x7FFFu + ((u >> 16) & 1u);
    return (ushort)(u >> 16);
}
__device__ __forceinline__ float bf2f(ushort u) {
    return __uint_as_float(((unsigned)u) << 16);
}

// ---------------- CSR build ----------------
// cnt/off are memset to 0 by host; the +1 self-loop is folded into scan1 and
// the scatter writes at row_ptr[dst] + 1 + p (slot 0 = self-loop).
__global__ void k_count(const int* __restrict__ ei, int* cnt) {
    int e = blockIdx.x * blockDim.x + threadIdx.x;
    if (e < N_EDGES) atomicAdd(&cnt[ei[N_EDGES + e]], 1);
}

__global__ __launch_bounds__(256) void k_scan1(const int* __restrict__ cnt,
                                               int* __restrict__ incl,
                                               int* __restrict__ partials) {
    __shared__ int sh[256];
    const int t = threadIdx.x;
    const int base = blockIdx.x * SCAN_ELEMS + t * 4;
    int v0 = 0, v1 = 0, v2 = 0, v3 = 0;
    if (base + 3 < N_NODES) {
        int4 lv = *reinterpret_cast<const int4*>(&cnt[base]);
        v0 = lv.x + 1; v1 = lv.y + 1; v2 = lv.z + 1; v3 = lv.w + 1;  // +1 self-loop
    } else {
        if (base + 0 < N_NODES) v0 = cnt[base + 0] + 1;
        if (base + 1 < N_NODES) v1 = cnt[base + 1] + 1;
        if (base + 2 < N_NODES) v2 = cnt[base + 2] + 1;
        if (base + 3 < N_NODES) v3 = cnt[base + 3] + 1;
    }
    const int s1 = v0 + v1, s2 = s1 + v2, s3 = s2 + v3;
    sh[t] = s3;
    __syncthreads();
#pragma unroll
    for (int off = 1; off < 256; off <<= 1) {
        int x = (t >= off) ? sh[t - off] : 0;
        __syncthreads();
        sh[t] += x;
        __syncthreads();
    }
    const int excl = sh[t] - s3;
    if (base + 0 < N_NODES) incl[base + 0] = excl + v0;
    if (base + 1 < N_NODES) incl[base + 1] = excl + s1;
    if (base + 2 < N_NODES) incl[base + 2] = excl + s2;
    if (base + 3 < N_NODES) incl[base + 3] = excl + s3;
    if (t == 255) partials[blockIdx.x] = sh[255];
}

// fused: per-block inline scan of 49 partials -> row_ptr + self-loop colb
__global__ void k_scan3self(const int* __restrict__ incl, const int* __restrict__ partials,
                            int* __restrict__ row_ptr, int* __restrict__ colb) {
    __shared__ int pofs_sh[SCAN_NB];
    if (threadIdx.x == 0) {
        int s = 0;
        for (int b = 0; b < SCAN_NB; ++b) { pofs_sh[b] = s; s += partials[b]; }
    }
    __syncthreads();
    int i = blockIdx.x * blockDim.x + threadIdx.x;
    if (i < N_NODES) {
        row_ptr[i + 1] = incl[i] + pofs_sh[i >> 10];
        int rp0 = (i == 0) ? 0 : (incl[i - 1] + pofs_sh[(i - 1) >> 10]);
        if (i == 0) row_ptr[0] = 0;
        colb[rp0] = i;  // self-loop at slot 0 of each row
    }
}

__global__ void k_scatter(const int* __restrict__ ei, const int* __restrict__ row_ptr,
                          int* off, int* colb) {
    int e = blockIdx.x * blockDim.x + threadIdx.x;
    if (e < N_EDGES) {
        int dst = ei[N_EDGES + e];
        int p = atomicAdd(&off[dst], 1);
        colb[row_ptr[dst] + 1 + p] = ei[e];  // +1: slot 0 is the self-loop
    }
}

// ---------------- fused prep: W1/W2/W3 transpose-convert + x convert ----------------
#define PREP_S1 (512 * 256)
#define PREP_S2 (512 * 512)
#define PREP_S3 (128 * 512)
#define PREP_S4 (N_NODES * 256 / 4)
__global__ void k_prep(const float* __restrict__ W1, const float* __restrict__ W2,
                       const float* __restrict__ W3, const float* __restrict__ x,
                       ushort* __restrict__ wt1, ushort* __restrict__ wt2,
                       ushort* __restrict__ wt3, ushort* __restrict__ hh) {
    int idx = blockIdx.x * blockDim.x + threadIdx.x;
    if (idx < PREP_S1) {
        int n = idx >> 8, k = idx & 255;                 // K=256, N=512
        wt1[idx] = f2bf(W1[(size_t)k * 512 + n]);
    } else if (idx < PREP_S1 + PREP_S2) {
        int j = idx - PREP_S1;
        int n = j >> 9, k = j & 511;                     // K=512, N=512
        wt2[j] = f2bf(W2[(size_t)k * 512 + n]);
    } else if (idx < PREP_S1 + PREP_S2 + PREP_S3) {
        int j = idx - PREP_S1 - PREP_S2;
        int n = j >> 9, k = j & 511;                     // K=512, N=128
        wt3[j] = f2bf(W3[(size_t)k * 128 + n]);
    } else if (idx < PREP_S1 + PREP_S2 + PREP_S3 + PREP_S4) {
        int j = idx - PREP_S1 - PREP_S2 - PREP_S3;
        float4 v = reinterpret_cast<const float4*>(x)[j];
        ushort4 o;
        o.x = f2bf(v.x); o.y = f2bf(v.y); o.z = f2bf(v.z); o.w = f2bf(v.w);
        reinterpret_cast<ushort4*>(hh)[j] = o;
    }
}

// ==== 128x256-tile bf16 MFMA GEMM, 8 waves, 64x64/wave, 2-phase LDS dbuf ====
// kslot-major chunk layout (conflict-free ds_read_b128): within each 16-row x 32-col
// chunk, LDS unit u (16B) holds global (row = u&15, kslot = u>>4). Staged by making
// lane i fetch (row = i&15, kslot = i>>4) -- LDS dest stays linear (rule #21).
__global__ __launch_bounds__(512) void k_gemm256(const ushort* __restrict__ A,
                                                 const ushort* __restrict__ Bt,
                                                 ushort* __restrict__ Cb,
                                                 const float* __restrict__ asrc,
                                                 const float* __restrict__ adst,
                                                 float* __restrict__ es,
                                                 float* __restrict__ ed,
                                                 int M, int K) {
    constexpr int N = 512;
    __shared__ __align__(16) ushort L[2][12288];    // 48 KB
    __shared__ float sles[4][128];                  // 2 KB
    __shared__ float sled[4][128];                  // 2 KB
    const int tid = threadIdx.x;
    const int wid = tid >> 6, lane = tid & 63;
    const int wm = wid >> 2, wn = wid & 3;

    // XCD-bijective swizzle (m204); row-tile = wg>>1, col-block = wg&1
    const int nwg = gridDim.x;
    const int q = nwg >> 3, r = nwg & 7;
    const int xcd = blockIdx.x & 7, bidx = blockIdx.x >> 3;
    const int wg = ((xcd < r) ? xcd * (q + 1) : r * (q + 1) + (xcd - r) * q) + bidx;
    const int row0 = (wg >> 1) * 128;
    const int by = wg & 1;
    const int col0 = by * 256;

    const int sub = lane & 15;         // row within 16-row chunk (kslot-major)
    const int kcol = (lane >> 4) * 8;  // element col in 32-wide K slab

    // staging: 24 chunks of 16 rows (A: 0..7, B: 8..23); wave owns chunks [wid*3,+3)
    const ushort* gPtr[3];
    int lOfs[3];
#pragma unroll
    for (int c = 0; c < 3; ++c) {
        int chunk = wid * 3 + c;
        lOfs[c] = chunk * 512;
        if (chunk < 8) {
            int ar = row0 + chunk * 16 + sub;
            if (ar > M - 1) ar = M - 1;
            gPtr[c] = A + (size_t)ar * K + kcol;
        } else {
            int bc = chunk - 8;
            gPtr[c] = Bt + (size_t)(col0 + bc * 16 + sub) * K + kcol;
        }
    }

    // fragment reads (kslot-major): offset = chunk*512 + (lane>>4)*128 + (lane&15)*8
    const int afr = wm * 2048 + (lane >> 4) * 128 + (lane & 15) * 8;
    const int bfr = 4096 + wn * 2048 + (lane >> 4) * 128 + (lane & 15) * 8;

    f32x4 acc[4][4] = {};

    // prologue: stage k0=0 into buf 0
#pragma unroll
    for (int c = 0; c < 3; ++c)
        __builtin_amdgcn_global_load_lds(
            (const __attribute__((address_space(1))) unsigned*)(gPtr[c]),
            (__attribute__((address_space(3))) unsigned*)(&L[0][lOfs[c]]), 16, 0, 0);
    __syncthreads();

    int cur = 0;
    for (int k0 = 32; k0 < K; k0 += 32) {
#pragma unroll
        for (int c = 0; c < 3; ++c)
            __builtin_amdgcn_global_load_lds(
                (const __attribute__((address_space(1))) unsigned*)(gPtr[c] + k0),
                (__attribute__((address_space(3))) unsigned*)(&L[cur ^ 1][lOfs[c]]), 16, 0, 0);
        {
            bf16x8 af[4], bg[4];
#pragma unroll
            for (int m = 0; m < 4; ++m)
                af[m] = *reinterpret_cast<const bf16x8*>(&L[cur][afr + m * 512]);
#pragma unroll
            for (int n = 0; n < 4; ++n)
                bg[n] = *reinterpret_cast<const bf16x8*>(&L[cur][bfr + n * 512]);
#pragma unroll
            for (int m = 0; m < 4; ++m)
#pragma unroll
                for (int n = 0; n < 4; ++n)
                    acc[m][n] = __builtin_amdgcn_mfma_f32_16x16x32_bf16(af[m], bg[n], acc[m][n], 0, 0, 0);
        }
        __syncthreads();
        cur ^= 1;
    }
    {
        bf16x8 af[4], bg[4];
#pragma unroll
        for (int m = 0; m < 4; ++m)
            af[m] = *reinterpret_cast<const bf16x8*>(&L[cur][afr + m * 512]);
#pragma unroll
        for (int n = 0; n < 4; ++n)
            bg[n] = *reinterpret_cast<const bf16x8*>(&L[cur][bfr + n * 512]);
#pragma unroll
        for (int m = 0; m < 4; ++m)
#pragma unroll
            for (int n = 0; n < 4; ++n)
                acc[m][n] = __builtin_amdgcn_mfma_f32_16x16x32_bf16(af[m], bg[n], acc[m][n], 0, 0, 0);
    }

    // ---- C write (bf16) ----
    const int crow = row0 + wm * 64 + (lane >> 4) * 4;
    const int ccol = col0 + wn * 64 + (lane & 15);
#pragma unroll
    for (int m = 0; m < 4; ++m) {
#pragma unroll
        for (int j = 0; j < 4; ++j) {
            int rr = crow + m * 16 + j;
            if (rr < M) {
#pragma unroll
                for (int n = 0; n < 4; ++n)
                    Cb[(size_t)rr * N + ccol + n * 16] = f2bf(acc[m][n][j]);
            }
        }
    }

    // ---- score epilogue: head = by*2 + (wn>>1); this wave covers half the head ----
    const int head = by * 2 + (wn >> 1);
    float as_c[4], ad_c[4];
#pragma unroll
    for (int n = 0; n < 4; ++n) {
        int cl = (wn & 1) * 64 + n * 16 + (lane & 15);
        as_c[n] = asrc[head * 128 + cl];
        ad_c[n] = adst[head * 128 + cl];
    }
#pragma unroll
    for (int m = 0; m < 4; ++m) {
#pragma unroll
        for (int j = 0; j < 4; ++j) {
            float ps = acc[m][0][j] * as_c[0] + acc[m][1][j] * as_c[1] +
                       acc[m][2][j] * as_c[2] + acc[m][3][j] * as_c[3];
            float pd = acc[m][0][j] * ad_c[0] + acc[m][1][j] * ad_c[1] +
                       acc[m][2][j] * ad_c[2] + acc[m][3][j] * ad_c[3];
#pragma unroll
            for (int o = 1; o < 16; o <<= 1) {
                ps += __shfl_xor(ps, o);
                pd += __shfl_xor(pd, o);
            }
            if ((lane & 15) == 0) {
                int rl = wm * 64 + (lane >> 4) * 4 + m * 16 + j;
                sles[wn][rl] = ps;
                sled[wn][rl] = pd;
            }
        }
    }
    __syncthreads();
    if (tid < 256) {
        const int hl = tid >> 7;          // head-local 0/1
        const int rl = tid & 127;
        const int rr = row0 + rl;
        if (rr < M) {
            es[(size_t)rr * 4 + by * 2 + hl] = sles[2 * hl][rl] + sles[2 * hl + 1][rl];
            ed[(size_t)rr * 4 + by * 2 + hl] = sled[2 * hl][rl] + sled[2 * hl + 1][rl];
        }
    }
}

// ---- 128x128 bf16 MFMA GEMM + fused score epilogue, 2-phase dbuf (layer 3, H=1) ----
__global__ __launch_bounds__(256) void k_gemm_bf16(const ushort* __restrict__ A,
                                                   const ushort* __restrict__ Bt,
                                                   ushort* __restrict__ Cb,
                                                   const float* __restrict__ asrc,
                                                   const float* __restrict__ adst,
                                                   float* __restrict__ es,
                                                   float* __restrict__ ed,
                                                   int M, int K, int N) {
    __shared__ __align__(16) ushort L[2][8192];  // A els 0..4095, B els 4096..8191; 32 KB
    __shared__ float sles[2][128];
    __shared__ float sled[2][128];
    const int tid = threadIdx.x;
    const int wid = tid >> 6, lane = tid & 63;
    const int wm = wid >> 1, wn = wid & 1;
    const int row0 = blockIdx.x * 128, col0 = blockIdx.y * 128;
    const int H = N >> 7;

    const int sub = lane & 15;         // kslot-major staging
    const int kcol = (lane >> 4) * 8;

    // 16 chunks (A: 0..7, B: 8..15); wave owns chunks [wid*4,+4)
    const ushort* gPtr[4];
    int lOfs[4];
#pragma unroll
    for (int c = 0; c < 4; ++c) {
        int chunk = wid * 4 + c;
        lOfs[c] = chunk * 512;
        if (chunk < 8) {
            int ar = row0 + chunk * 16 + sub;
            if (ar > M - 1) ar = M - 1;
            gPtr[c] = A + (size_t)ar * K + kcol;
        } else {
            int bc = chunk - 8;
            gPtr[c] = Bt + (size_t)(col0 + bc * 16 + sub) * K + kcol;
        }
    }

    const int afr = wm * 2048 + (lane >> 4) * 128 + (lane & 15) * 8;
    const int bfr = 4096 + wn * 2048 + (lane >> 4) * 128 + (lane & 15) * 8;

    f32x4 acc[4][4] = {};

#pragma unroll
    for (int c = 0; c < 4; ++c)
        __builtin_amdgcn_global_load_lds(
            (const __attribute__((address_space(1))) unsigned*)(gPtr[c]),
            (__attribute__((address_space(3))) unsigned*)(&L[0][lOfs[c]]), 16, 0, 0);
    __syncthreads();

    int cur = 0;
    for (int k0 = 32; k0 < K; k0 += 32) {
#pragma unroll
        for (int c = 0; c < 4; ++c)
            __builtin_amdgcn_global_load_lds(
                (const __attribute__((address_space(1))) unsigned*)(gPtr[c] + k0),
                (__attribute__((address_space(3))) unsigned*)(&L[cur ^ 1][lOfs[c]]), 16, 0, 0);
        {
            bf16x8 af[4], bg[4];
#pragma unroll
            for (int m = 0; m < 4; ++m)
                af[m] = *reinterpret_cast<const bf16x8*>(&L[cur][afr + m * 512]);
#pragma unroll
            for (int n = 0; n < 4; ++n)
                bg[n] = *reinterpret_cast<const bf16x8*>(&L[cur][bfr + n * 512]);
#pragma unroll
            for (int m = 0; m < 4; ++m)
#pragma unroll
                for (int n = 0; n < 4; ++n)
                    acc[m][n] = __builtin_amdgcn_mfma_f32_16x16x32_bf16(af[m], bg[n], acc[m][n], 0, 0, 0);
        }
        __syncthreads();
        cur ^= 1;
    }
    {
        bf16x8 af[4], bg[4];
#pragma unroll
        for (int m = 0; m < 4; ++m)
            af[m] = *reinterpret_cast<const bf16x8*>(&L[cur][afr + m * 512]);
#pragma unroll
        for (int n = 0; n < 4; ++n)
            bg[n] = *reinterpret_cast<const bf16x8*>(&L[cur][bfr + n * 512]);
#pragma unroll
        for (int m = 0; m < 4; ++m)
#pragma unroll
            for (int n = 0; n < 4; ++n)
                acc[m][n] = __builtin_amdgcn_mfma_f32_16x16x32_bf16(af[m], bg[n], acc[m][n], 0, 0, 0);
    }

    const int crow = row0 + wm * 64 + (lane >> 4) * 4;
    const int ccol = col0 + wn * 64 + (lane & 15);
#pragma unroll
    for (int m = 0; m < 4; ++m) {
#pragma unroll
        for (int j = 0; j < 4; ++j) {
            int r = crow + m * 16 + j;
            if (r < M) {
#pragma unroll
                for (int n = 0; n < 4; ++n)
                    Cb[(size_t)r * N + ccol + n * 16] = f2bf(acc[m][n][j]);
            }
        }
    }

    float as_c[4], ad_c[4];
#pragma unroll
    for (int n = 0; n < 4; ++n) {
        int cl = wn * 64 + n * 16 + (lane & 15);
        as_c[n] = asrc[blockIdx.y * 128 + cl];
        ad_c[n] = adst[blockIdx.y * 128 + cl];
    }
#pragma unroll
    for (int m = 0; m < 4; ++m) {
#pragma unroll
        for (int j = 0; j < 4; ++j) {
            float ps = acc[m][0][j] * as_c[0] + acc[m][1][j] * as_c[1] +
                       acc[m][2][j] * as_c[2] + acc[m][3][j] * as_c[3];
            float pd = acc[m][0][j] * ad_c[0] + acc[m][1][j] * ad_c[1] +
                       acc[m][2][j] * ad_c[2] + acc[m][3][j] * ad_c[3];
#pragma unroll
            for (int o = 1; o < 16; o <<= 1) {
                ps += __shfl_xor(ps, o);
                pd += __shfl_xor(pd, o);
            }
            if ((lane & 15) == 0) {
                int rl = wm * 64 + (lane >> 4) * 4 + m * 16 + j;
                sles[wn][rl] = ps;
                sled[wn][rl] = pd;
            }
        }
    }
    __syncthreads();
    if (tid < 128) {
        int r = row0 + tid;
        if (r < M) {
            es[(size_t)r * H + blockIdx.y] = sles[0][tid] + sles[1][tid];
            ed[(size_t)r * H + blockIdx.y] = sled[0][tid] + sled[1][tid];
        }
    }
}

// ---- wave-per-node softmax aggregation + bias + BN + ReLU ----
template <int H, bool BF16OUT>
__global__ __launch_bounds__(64) void k_agg(
    const ushort* __restrict__ xpb, const float* __restrict__ es, const float* __restrict__ ed,
    const int* __restrict__ row_ptr, const int* __restrict__ colb,
    const float* __restrict__ bias, const float* __restrict__ gg, const float* __restrict__ be,
    const float* __restrict__ mu, const float* __restrict__ var, void* __restrict__ outv) {
    constexpr int HC = H * 128;
    constexpr int CPT = HC / 64;  // 8 (H=4) or 2 (H=1)
    constexpr int CHUNK = 128;
    constexpr int GS = (H == 4) ? 16 : 64;
    __shared__ int s_src[CHUNK];
    __shared__ float s_w[CHUNK][H];
    const int n = blockIdx.x;
    const int lane = threadIdx.x;
    const int g = (H == 4) ? (lane >> 4) : 0;
    const int gl = (H == 4) ? (lane & 15) : lane;
    const int beg = row_ptr[n], end = row_ptr[n + 1];
    const int cnt = end - beg;

    float edn[H];
#pragma unroll
    for (int h = 0; h < H; ++h) edn[h] = ed[n * H + h];

    float acc[CPT];
#pragma unroll
    for (int j = 0; j < CPT; ++j) acc[j] = 0.f;
    float m_run = -INFINITY, s_run = 0.f;
    const int ch0 = lane * CPT;
    const ushort* xb = xpb + ch0;

    for (int cbeg = 0; cbeg < cnt; cbeg += CHUNK) {
        const int cc = min(cnt - cbeg, CHUNK);
        for (int i = lane; i < cc; i += 64) {
            int src = colb[beg + cbeg + i];
            s_src[i] = src;
            if (H == 4) {
                float4 e4 = *reinterpret_cast<const float4*>(&es[src * 4]);
                float4 o;
                o.x = e4.x + edn[0]; o.x = (o.x > 0.f) ? o.x : NEG_SLOPE * o.x;
                o.y = e4.y + edn[1]; o.y = (o.y > 0.f) ? o.y : NEG_SLOPE * o.y;
                o.z = e4.z + edn[2]; o.z = (o.z > 0.f) ? o.z : NEG_SLOPE * o.z;
                o.w = e4.w + edn[3]; o.w = (o.w > 0.f) ? o.w : NEG_SLOPE * o.w;
                *reinterpret_cast<float4*>(&s_w[i][0]) = o;
            } else {
                float e = es[src] + edn[0];
                s_w[i][0] = (e > 0.f) ? e : NEG_SLOPE * e;
            }
        }
        __syncthreads();
        float cm = -INFINITY;
        for (int i = gl; i < cc; i += GS) cm = fmaxf(cm, s_w[i][g]);
#pragma unroll
        for (int o = GS >> 1; o; o >>= 1) cm = fmaxf(cm, __shfl_xor(cm, o));
        const float m_new = fmaxf(m_run, cm);
        const float scale = __expf(m_run - m_new);  // first chunk: exp(-inf)=0
        float sl = 0.f;
        for (int i = gl; i < cc; i += GS) {
            float w = __expf(s_w[i][g] - m_new);
            s_w[i][g] = w;
            sl += w;
        }
#pragma unroll
        for (int o = GS >> 1; o; o >>= 1) sl += __shfl_xor(sl, o);
        s_run = s_run * scale + sl;
        m_run = m_new;
#pragma unroll
        for (int j = 0; j < CPT; ++j) acc[j] *= scale;
        __syncthreads();
        for (int e = 0; e < cc; e += 4) {
            float w0 = s_w[e][g];
            int   p0 = s_src[e];
            float w1 = 0.f; int p1 = n;
            float w2 = 0.f; int p2 = n;
            float w3 = 0.f; int p3 = n;
            if (e + 1 < cc) { w1 = s_w[e + 1][g]; p1 = s_src[e + 1]; }
            if (e + 2 < cc) { w2 = s_w[e + 2][g]; p2 = s_src[e + 2]; }
            if (e + 3 < cc) { w3 = s_w[e + 3][g]; p3 = s_src[e + 3]; }
            if (CPT == 8) {
                u16x8 v0 = *reinterpret_cast<const u16x8*>(xb + (size_t)p0 * HC);
                u16x8 v1 = *reinterpret_cast<const u16x8*>(xb + (size_t)p1 * HC);
                u16x8 v2 = *reinterpret_cast<const u16x8*>(xb + (size_t)p2 * HC);
                u16x8 v3 = *reinterpret_cast<const u16x8*>(xb + (size_t)p3 * HC);
#pragma unroll
                for (int j = 0; j < CPT; ++j) {
                    float a = acc[j];
                    a = fmaf(w0, bf2f(v0[j]), a);
                    a = fmaf(w1, bf2f(v1[j]), a);
                    a = fmaf(w2, bf2f(v2[j]), a);
                    a = fmaf(w3, bf2f(v3[j]), a);
                    acc[j] = a;
                }
            } else {
                u16x2 v0 = *reinterpret_cast<const u16x2*>(xb + (size_t)p0 * HC);
                u16x2 v1 = *reinterpret_cast<const u16x2*>(xb + (size_t)p1 * HC);
                u16x2 v2 = *reinterpret_cast<const u16x2*>(xb + (size_t)p2 * HC);
                u16x2 v3 = *reinterpret_cast<const u16x2*>(xb + (size_t)p3 * HC);
#pragma unroll
                for (int j = 0; j < CPT; ++j) {
                    float a = acc[j];
                    a = fmaf(w0, bf2f(v0[j]), a);
                    a = fmaf(w1, bf2f(v1[j]), a);
                    a = fmaf(w2, bf2f(v2[j]), a);
                    a = fmaf(w3, bf2f(v3[j]), a);
                    acc[j] = a;
                }
            }
        }
        __syncthreads();
    }

    const float inv = 1.f / (s_run + 1e-16f);
    float vals[CPT];
#pragma unroll
    for (int j = 0; j < CPT; ++j) {
        int ch = ch0 + j;
        float val = acc[j] * inv + bias[ch];
        val = (val - mu[ch]) * (gg[ch] * rsqrtf(var[ch] + BN_EPS)) + be[ch];
        vals[j] = fmaxf(val, 0.f);
    }
    if (BF16OUT) {
        if (CPT == 8) {
            u16x8 o;
#pragma unroll
            for (int j = 0; j < CPT; ++j) o[j] = f2bf(vals[j]);
            *reinterpret_cast<u16x8*>((ushort*)outv + (size_t)n * HC + ch0) = o;
        } else {
            u16x2 o;
#pragma unroll
            for (int j = 0; j < CPT; ++j) o[j] = f2bf(vals[j]);
            *reinterpret_cast<u16x2*>((ushort*)outv + (size_t)n * HC + ch0) = o;
        }
    } else {
        float2 o = make_float2(vals[0], vals[1 % CPT]);
        *reinterpret_cast<float2*>((float*)outv + (size_t)n * HC + ch0) = o;
    }
}

// ---------------- classifier: LDS-staged, 16 nodes / 256-thread block ----------------
#define CLS_NB 16
__global__ __launch_bounds__(256) void k_cls(const float* __restrict__ Eg,
                                             const float* __restrict__ Wc1,
                                             const float* __restrict__ bc1,
                                             const float* __restrict__ Wc2,
                                             const float* __restrict__ bc2,
                                             float* __restrict__ P) {
    __shared__ float Ws[128 * 64];
    __shared__ float W2s[64 * 10 + 16];
    __shared__ float b1s[64];
    __shared__ float e_sh[CLS_NB][128];
    __shared__ float h_sh[CLS_NB][64];
    __shared__ float l_sh[CLS_NB][10];
    const int t = threadIdx.x;
    const int n0 = blockIdx.x * CLS_NB;

    for (int i = t; i < 2048; i += 256)
        reinterpret_cast<float4*>(Ws)[i] = reinterpret_cast<const float4*>(Wc1)[i];
    for (int i = t; i < 640; i += 256) W2s[i] = Wc2[i];
    if (t < 64) b1s[t] = bc1[t];
    if (t >= 64 && t < 74) W2s[640 + t - 64] = bc2[t - 64];
    for (int i = t; i < CLS_NB * 32; i += 256) {
        int node = i >> 5, qq = i & 31;
        reinterpret_cast<float4*>(&e_sh[node][0])[qq] =
            reinterpret_cast<const float4*>(&Eg[(size_t)(n0 + node) * 128])[qq];
    }
    __syncthreads();

    {
        const int c = t & 63, ng = t >> 6;
        float acc0 = b1s[c], acc1 = b1s[c], acc2 = b1s[c], acc3 = b1s[c];
        for (int k = 0; k < 128; ++k) {
            float w = Ws[k * 64 + c];
            acc0 = fmaf(e_sh[ng * 4 + 0][k], w, acc0);
            acc1 = fmaf(e_sh[ng * 4 + 1][k], w, acc1);
            acc2 = fmaf(e_sh[ng * 4 + 2][k], w, acc2);
            acc3 = fmaf(e_sh[ng * 4 + 3][k], w, acc3);
        }
        h_sh[ng * 4 + 0][c] = fmaxf(acc0, 0.f);
        h_sh[ng * 4 + 1][c] = fmaxf(acc1, 0.f);
        h_sh[ng * 4 + 2][c] = fmaxf(acc2, 0.f);
        h_sh[ng * 4 + 3][c] = fmaxf(acc3, 0.f);
    }
    __syncthreads();
    if (t < CLS_NB * 10) {
        int node = t / 10, c = t - node * 10;
        float acc = W2s[640 + c];
        for (int k = 0; k < 64; ++k) acc = fmaf(h_sh[node][k], W2s[k * 10 + c], acc);
        l_sh[node][c] = acc;
    }
    __syncthreads();
    if (t < CLS_NB) {
        float mx = l_sh[t][0];
        for (int j = 1; j < 10; ++j) mx = fmaxf(mx, l_sh[t][j]);
        float s = 0.f;
        float ex[10];
        for (int j = 0; j < 10; ++j) { ex[j] = __expf(l_sh[t][j] - mx); s += ex[j]; }
        float inv = 1.f / s;
        for (int j = 0; j < 10; ++j) l_sh[t][j] = ex[j] * inv;
    }
    __syncthreads();
    if (t < CLS_NB * 10) {
        int node = t / 10, c = t - node * 10;
        P[(size_t)(n0 + node) * 10 + c] = l_sh[node][c];
    }
}

extern "C" void kernel_launch(void* const* d_in, const int* in_sizes, int n_in,
                              void* d_out, int out_size, void* d_ws, size_t ws_size,
                              hipStream_t stream) {
    const float* x     = (const float*)d_in[0];
    const int*   ei    = (const int*)d_in[1];
    const float* W1    = (const float*)d_in[2];
    const float* asrc1 = (const float*)d_in[3];
    const float* adst1 = (const float*)d_in[4];
    const float* b1    = (const float*)d_in[5];
    const float* gg1   = (const float*)d_in[6];
    const float* be1   = (const float*)d_in[7];
    const float* mu1   = (const float*)d_in[8];
    const float* v1    = (const float*)d_in[9];
    const float* W2    = (const float*)d_in[10];
    const float* asrc2 = (const float*)d_in[11];
    const float* adst2 = (const float*)d_in[12];
    const float* b2    = (const float*)d_in[13];
    const float* gg2   = (const float*)d_in[14];
    const float* be2   = (const float*)d_in[15];
    const float* mu2   = (const float*)d_in[16];
    const float* v2    = (const float*)d_in[17];
    const float* W3    = (const float*)d_in[18];
    const float* asrc3 = (const float*)d_in[19];
    const float* adst3 = (const float*)d_in[20];
    const float* b3    = (const float*)d_in[21];
    const float* gg3   = (const float*)d_in[22];
    const float* be3   = (const float*)d_in[23];
    const float* mu3   = (const float*)d_in[24];
    const float* v3    = (const float*)d_in[25];
    const float* Wc1   = (const float*)d_in[26];
    const float* bc1   = (const float*)d_in[27];
    const float* Wc2   = (const float*)d_in[28];
    const float* bc2   = (const float*)d_in[29];

    // ---- workspace layout (~107 MB) ----
    ushort* xpb  = (ushort*)d_ws;                      // bf16 xp, N*512
    ushort* hh   = xpb + (size_t)N_NODES * 512;        // bf16 GEMM input, N*512
    ushort* wt1  = hh + (size_t)N_NODES * 512;         // 512*256
    ushort* wt2  = wt1 + 512 * 256;                    // 512*512
    ushort* wt3  = wt2 + 512 * 512;                    // 128*512
    float*  es   = (float*)(wt3 + 128 * 512);
    float*  ed   = es + (size_t)N_NODES * 4;
    int* cnt     = (int*)(ed + (size_t)N_NODES * 4);
    int* off     = cnt + N_NODES;
    int* row_ptr = off + N_NODES;
    int* colb    = row_ptr + N_NODES + 4;
    int* incl    = colb + N_EDGES + N_NODES;
    int* partials = incl + N_NODES;

    float* Egnn = (float*)d_out;
    float* P    = Egnn + (size_t)N_NODES * 128;

    // ---- CSR build (cnt+off zeroed by one memset; +1 folded into scan1/scatter) ----
    hipMemsetAsync(cnt, 0, 2 * (size_t)N_NODES * sizeof(int), stream);
    k_count<<<(N_EDGES + 255) / 256, 256, 0, stream>>>(ei, cnt);
    k_scan1<<<SCAN_NB, 256, 0, stream>>>(cnt, incl, partials);
    k_scan3self<<<(N_NODES + 255) / 256, 256, 0, stream>>>(incl, partials, row_ptr, colb);
    k_scatter<<<(N_EDGES + 255) / 256, 256, 0, stream>>>(ei, row_ptr, off, colb);

    // ---- fused weight transpose-converts + x convert ----
    {
        int total = PREP_S1 + PREP_S2 + PREP_S3 + PREP_S4;
        k_prep<<<(total + 255) / 256, 256, 0, stream>>>(W1, W2, W3, x, wt1, wt2, wt3, hh);
    }

    const int mt = (N_NODES + 127) / 128;  // 391
    const int nwg256 = mt * 2;             // 782 (column-block fastest)

    // ---- layer 1: 256 -> 4x128 ----
    k_gemm256<<<nwg256, 512, 0, stream>>>(hh, wt1, xpb, asrc1, adst1, es, ed,
                                          N_NODES, 256);
    k_agg<4, true><<<N_NODES, 64, 0, stream>>>(xpb, es, ed, row_ptr, colb,
                                               b1, gg1, be1, mu1, v1, hh);
    // ---- layer 2: 512 -> 4x128 ----
    k_gemm256<<<nwg256, 512, 0, stream>>>(hh, wt2, xpb, asrc2, adst2, es, ed,
                                          N_NODES, 512);
    k_agg<4, true><<<N_NODES, 64, 0, stream>>>(xpb, es, ed, row_ptr, colb,
                                               b2, gg2, be2, mu2, v2, hh);
    // ---- layer 3: 512 -> 1x128 ----
    {
        dim3 grid(mt, 1);
        k_gemm_bf16<<<grid, 256, 0, stream>>>(hh, wt3, xpb, asrc3, adst3, es, ed,
                                              N_NODES, 512, 128);
    }
    k_agg<1, false><<<N_NODES, 64, 0, stream>>>(xpb, es, ed, row_ptr, colb,
                                                b3, gg3, be3, mu3, v3, Egnn);
    // ---- classifier ----
    k_cls<<<(N_NODES + CLS_NB - 1) / CLS_NB, 256, 0, stream>>>(Egnn, Wc1, bc1, Wc2, bc2, P);
}

// Round 14
// 441.006 us; speedup vs baseline: 1.0438x; 1.0438x over previous
//
#include <hip/hip_runtime.h>
#include <math.h>

#define N_NODES 50000
#define N_EDGES 200000
#define NEG_SLOPE 0.2f
#define BN_EPS 1e-5f

#define SCAN_ELEMS 1024
#define SCAN_NB ((N_NODES + SCAN_ELEMS - 1) / SCAN_ELEMS)  // 49

typedef __attribute__((ext_vector_type(4))) float f32x4;
typedef __attribute__((ext_vector_type(8))) short bf16x8;
typedef __attribute__((ext_vector_type(8))) ushort u16x8;
typedef __attribute__((ext_vector_type(2))) ushort u16x2;

__device__ __forceinline__ ushort f2bf(float x) {
    unsigned u = __float_as_uint(x);
    u += 0x7FFFu + ((u >> 16) & 1u);
    return (ushort)(u >> 16);
}
__device__ __forceinline__ float bf2f(ushort u) {
    return __uint_as_float(((unsigned)u) << 16);
}

// ---------------- CSR build ----------------
__global__ void k_count(const int* __restrict__ ei, int* cnt) {
    int e = blockIdx.x * blockDim.x + threadIdx.x;
    if (e < N_EDGES) atomicAdd(&cnt[ei[N_EDGES + e]], 1);
}

__global__ __launch_bounds__(256) void k_scan1(const int* __restrict__ cnt,
                                               int* __restrict__ incl,
                                               int* __restrict__ partials) {
    __shared__ int sh[256];
    const int t = threadIdx.x;
    const int base = blockIdx.x * SCAN_ELEMS + t * 4;
    int v0 = 0, v1 = 0, v2 = 0, v3 = 0;
    if (base + 3 < N_NODES) {
        int4 lv = *reinterpret_cast<const int4*>(&cnt[base]);
        v0 = lv.x + 1; v1 = lv.y + 1; v2 = lv.z + 1; v3 = lv.w + 1;  // +1 self-loop
    } else {
        if (base + 0 < N_NODES) v0 = cnt[base + 0] + 1;
        if (base + 1 < N_NODES) v1 = cnt[base + 1] + 1;
        if (base + 2 < N_NODES) v2 = cnt[base + 2] + 1;
        if (base + 3 < N_NODES) v3 = cnt[base + 3] + 1;
    }
    const int s1 = v0 + v1, s2 = s1 + v2, s3 = s2 + v3;
    sh[t] = s3;
    __syncthreads();
#pragma unroll
    for (int off = 1; off < 256; off <<= 1) {
        int x = (t >= off) ? sh[t - off] : 0;
        __syncthreads();
        sh[t] += x;
        __syncthreads();
    }
    const int excl = sh[t] - s3;
    if (base + 0 < N_NODES) incl[base + 0] = excl + v0;
    if (base + 1 < N_NODES) incl[base + 1] = excl + s1;
    if (base + 2 < N_NODES) incl[base + 2] = excl + s2;
    if (base + 3 < N_NODES) incl[base + 3] = excl + s3;
    if (t == 255) partials[blockIdx.x] = sh[255];
}

__global__ void k_scan3self(const int* __restrict__ incl, const int* __restrict__ partials,
                            int* __restrict__ row_ptr, int* __restrict__ colb) {
    __shared__ int pofs_sh[SCAN_NB];
    if (threadIdx.x == 0) {
        int s = 0;
        for (int b = 0; b < SCAN_NB; ++b) { pofs_sh[b] = s; s += partials[b]; }
    }
    __syncthreads();
    int i = blockIdx.x * blockDim.x + threadIdx.x;
    if (i < N_NODES) {
        row_ptr[i + 1] = incl[i] + pofs_sh[i >> 10];
        int rp0 = (i == 0) ? 0 : (incl[i - 1] + pofs_sh[(i - 1) >> 10]);
        if (i == 0) row_ptr[0] = 0;
        colb[rp0] = i;  // self-loop at slot 0 of each row
    }
}

__global__ void k_scatter(const int* __restrict__ ei, const int* __restrict__ row_ptr,
                          int* off, int* colb) {
    int e = blockIdx.x * blockDim.x + threadIdx.x;
    if (e < N_EDGES) {
        int dst = ei[N_EDGES + e];
        int p = atomicAdd(&off[dst], 1);
        colb[row_ptr[dst] + 1 + p] = ei[e];  // +1: slot 0 is the self-loop
    }
}

// ---------------- fused prep: W1/W2/W3 transpose-convert + x convert ----------------
#define PREP_S1 (512 * 256)
#define PREP_S2 (512 * 512)
#define PREP_S3 (128 * 512)
#define PREP_S4 (N_NODES * 256 / 4)
__global__ void k_prep(const float* __restrict__ W1, const float* __restrict__ W2,
                       const float* __restrict__ W3, const float* __restrict__ x,
                       ushort* __restrict__ wt1, ushort* __restrict__ wt2,
                       ushort* __restrict__ wt3, ushort* __restrict__ hh) {
    int idx = blockIdx.x * blockDim.x + threadIdx.x;
    if (idx < PREP_S1) {
        int n = idx >> 8, k = idx & 255;                 // K=256, N=512
        wt1[idx] = f2bf(W1[(size_t)k * 512 + n]);
    } else if (idx < PREP_S1 + PREP_S2) {
        int j = idx - PREP_S1;
        int n = j >> 9, k = j & 511;                     // K=512, N=512
        wt2[j] = f2bf(W2[(size_t)k * 512 + n]);
    } else if (idx < PREP_S1 + PREP_S2 + PREP_S3) {
        int j = idx - PREP_S1 - PREP_S2;
        int n = j >> 9, k = j & 511;                     // K=512, N=128
        wt3[j] = f2bf(W3[(size_t)k * 128 + n]);
    } else if (idx < PREP_S1 + PREP_S2 + PREP_S3 + PREP_S4) {
        int j = idx - PREP_S1 - PREP_S2 - PREP_S3;
        float4 v = reinterpret_cast<const float4*>(x)[j];
        ushort4 o;
        o.x = f2bf(v.x); o.y = f2bf(v.y); o.z = f2bf(v.z); o.w = f2bf(v.w);
        reinterpret_cast<ushort4*>(hh)[j] = o;
    }
}

// ==== 128x256-tile bf16 MFMA GEMM, 8 waves, 64x64/wave, 2-phase LDS dbuf ====
// XOR kslot swizzle (rule #21): lane i fetches (row=i>>2, kslot=(i&3)^((i>>2)&3)),
// LDS dest linear; fragment read unit = 4*(l&15) + ((l>>4)^(l&3)).
// Coalescing: lanes 4r..4r+3 cover one contiguous 64B row segment (permuted inside).
// Bank conflicts: 2 lanes/bank-group = free (m136).
__global__ __launch_bounds__(512) void k_gemm256(const ushort* __restrict__ A,
                                                 const ushort* __restrict__ Bt,
                                                 ushort* __restrict__ Cb,
                                                 const float* __restrict__ asrc,
                                                 const float* __restrict__ adst,
                                                 float* __restrict__ es,
                                                 float* __restrict__ ed,
                                                 int M, int K) {
    constexpr int N = 512;
    __shared__ __align__(16) ushort L[2][12288];    // 48 KB
    __shared__ float sles[4][128];                  // 2 KB
    __shared__ float sled[4][128];                  // 2 KB
    const int tid = threadIdx.x;
    const int wid = tid >> 6, lane = tid & 63;
    const int wm = wid >> 2, wn = wid & 3;

    // XCD-bijective swizzle (m204); row-tile = wg>>1, col-block = wg&1
    const int nwg = gridDim.x;
    const int q = nwg >> 3, r = nwg & 7;
    const int xcd = blockIdx.x & 7, bidx = blockIdx.x >> 3;
    const int wg = ((xcd < r) ? xcd * (q + 1) : r * (q + 1) + (xcd - r) * q) + bidx;
    const int row0 = (wg >> 1) * 128;
    const int by = wg & 1;
    const int col0 = by * 256;

    const int sub = lane >> 2;                         // row within 16-row chunk
    const int kcol = (((lane & 3) ^ (sub & 3))) * 8;   // XOR-swizzled kslot

    // staging: 24 chunks of 16 rows (A: 0..7, B: 8..23); wave owns chunks [wid*3,+3)
    const ushort* gPtr[3];
    int lOfs[3];
#pragma unroll
    for (int c = 0; c < 3; ++c) {
        int chunk = wid * 3 + c;
        lOfs[c] = chunk * 512;
        if (chunk < 8) {
            int ar = row0 + chunk * 16 + sub;
            if (ar > M - 1) ar = M - 1;
            gPtr[c] = A + (size_t)ar * K + kcol;
        } else {
            int bc = chunk - 8;
            gPtr[c] = Bt + (size_t)(col0 + bc * 16 + sub) * K + kcol;
        }
    }

    // fragment reads: unit within chunk = 4*(l&15) + ((l>>4)^(l&3)); x8 elements
    const int fu = (4 * (lane & 15) + ((lane >> 4) ^ (lane & 3))) * 8;
    const int afr = wm * 2048 + fu;
    const int bfr = 4096 + wn * 2048 + fu;

    f32x4 acc[4][4] = {};

    // prologue: stage k0=0 into buf 0
#pragma unroll
    for (int c = 0; c < 3; ++c)
        __builtin_amdgcn_global_load_lds(
            (const __attribute__((address_space(1))) unsigned*)(gPtr[c]),
            (__attribute__((address_space(3))) unsigned*)(&L[0][lOfs[c]]), 16, 0, 0);
    __syncthreads();

    int cur = 0;
    for (int k0 = 32; k0 < K; k0 += 32) {
#pragma unroll
        for (int c = 0; c < 3; ++c)
            __builtin_amdgcn_global_load_lds(
                (const __attribute__((address_space(1))) unsigned*)(gPtr[c] + k0),
                (__attribute__((address_space(3))) unsigned*)(&L[cur ^ 1][lOfs[c]]), 16, 0, 0);
        {
            bf16x8 af[4], bg[4];
#pragma unroll
            for (int m = 0; m < 4; ++m)
                af[m] = *reinterpret_cast<const bf16x8*>(&L[cur][afr + m * 512]);
#pragma unroll
            for (int n = 0; n < 4; ++n)
                bg[n] = *reinterpret_cast<const bf16x8*>(&L[cur][bfr + n * 512]);
#pragma unroll
            for (int m = 0; m < 4; ++m)
#pragma unroll
                for (int n = 0; n < 4; ++n)
                    acc[m][n] = __builtin_amdgcn_mfma_f32_16x16x32_bf16(af[m], bg[n], acc[m][n], 0, 0, 0);
        }
        __syncthreads();
        cur ^= 1;
    }
    {
        bf16x8 af[4], bg[4];
#pragma unroll
        for (int m = 0; m < 4; ++m)
            af[m] = *reinterpret_cast<const bf16x8*>(&L[cur][afr + m * 512]);
#pragma unroll
        for (int n = 0; n < 4; ++n)
            bg[n] = *reinterpret_cast<const bf16x8*>(&L[cur][bfr + n * 512]);
#pragma unroll
        for (int m = 0; m < 4; ++m)
#pragma unroll
            for (int n = 0; n < 4; ++n)
                acc[m][n] = __builtin_amdgcn_mfma_f32_16x16x32_bf16(af[m], bg[n], acc[m][n], 0, 0, 0);
    }

    // ---- C write (bf16) ----
    const int crow = row0 + wm * 64 + (lane >> 4) * 4;
    const int ccol = col0 + wn * 64 + (lane & 15);
#pragma unroll
    for (int m = 0; m < 4; ++m) {
#pragma unroll
        for (int j = 0; j < 4; ++j) {
            int rr = crow + m * 16 + j;
            if (rr < M) {
#pragma unroll
                for (int n = 0; n < 4; ++n)
                    Cb[(size_t)rr * N + ccol + n * 16] = f2bf(acc[m][n][j]);
            }
        }
    }

    // ---- score epilogue: head = by*2 + (wn>>1); this wave covers half the head ----
    const int head = by * 2 + (wn >> 1);
    float as_c[4], ad_c[4];
#pragma unroll
    for (int n = 0; n < 4; ++n) {
        int cl = (wn & 1) * 64 + n * 16 + (lane & 15);
        as_c[n] = asrc[head * 128 + cl];
        ad_c[n] = adst[head * 128 + cl];
    }
#pragma unroll
    for (int m = 0; m < 4; ++m) {
#pragma unroll
        for (int j = 0; j < 4; ++j) {
            float ps = acc[m][0][j] * as_c[0] + acc[m][1][j] * as_c[1] +
                       acc[m][2][j] * as_c[2] + acc[m][3][j] * as_c[3];
            float pd = acc[m][0][j] * ad_c[0] + acc[m][1][j] * ad_c[1] +
                       acc[m][2][j] * ad_c[2] + acc[m][3][j] * ad_c[3];
#pragma unroll
            for (int o = 1; o < 16; o <<= 1) {
                ps += __shfl_xor(ps, o);
                pd += __shfl_xor(pd, o);
            }
            if ((lane & 15) == 0) {
                int rl = wm * 64 + (lane >> 4) * 4 + m * 16 + j;
                sles[wn][rl] = ps;
                sled[wn][rl] = pd;
            }
        }
    }
    __syncthreads();
    if (tid < 256) {
        const int hl = tid >> 7;          // head-local 0/1
        const int rl = tid & 127;
        const int rr = row0 + rl;
        if (rr < M) {
            es[(size_t)rr * 4 + by * 2 + hl] = sles[2 * hl][rl] + sles[2 * hl + 1][rl];
            ed[(size_t)rr * 4 + by * 2 + hl] = sled[2 * hl][rl] + sled[2 * hl + 1][rl];
        }
    }
}

// ---- 128x128 bf16 MFMA GEMM + fused score epilogue, 2-phase dbuf (layer 3, H=1) ----
__global__ __launch_bounds__(256) void k_gemm_bf16(const ushort* __restrict__ A,
                                                   const ushort* __restrict__ Bt,
                                                   ushort* __restrict__ Cb,
                                                   const float* __restrict__ asrc,
                                                   const float* __restrict__ adst,
                                                   float* __restrict__ es,
                                                   float* __restrict__ ed,
                                                   int M, int K, int N) {
    __shared__ __align__(16) ushort L[2][8192];  // A els 0..4095, B els 4096..8191; 32 KB
    __shared__ float sles[2][128];
    __shared__ float sled[2][128];
    const int tid = threadIdx.x;
    const int wid = tid >> 6, lane = tid & 63;
    const int wm = wid >> 1, wn = wid & 1;
    const int row0 = blockIdx.x * 128, col0 = blockIdx.y * 128;
    const int H = N >> 7;

    const int sub = lane >> 2;
    const int kcol = (((lane & 3) ^ (sub & 3))) * 8;   // XOR-swizzled kslot

    // 16 chunks (A: 0..7, B: 8..15); wave owns chunks [wid*4,+4)
    const ushort* gPtr[4];
    int lOfs[4];
#pragma unroll
    for (int c = 0; c < 4; ++c) {
        int chunk = wid * 4 + c;
        lOfs[c] = chunk * 512;
        if (chunk < 8) {
            int ar = row0 + chunk * 16 + sub;
            if (ar > M - 1) ar = M - 1;
            gPtr[c] = A + (size_t)ar * K + kcol;
        } else {
            int bc = chunk - 8;
            gPtr[c] = Bt + (size_t)(col0 + bc * 16 + sub) * K + kcol;
        }
    }

    const int fu = (4 * (lane & 15) + ((lane >> 4) ^ (lane & 3))) * 8;
    const int afr = wm * 2048 + fu;
    const int bfr = 4096 + wn * 2048 + fu;

    f32x4 acc[4][4] = {};

#pragma unroll
    for (int c = 0; c < 4; ++c)
        __builtin_amdgcn_global_load_lds(
            (const __attribute__((address_space(1))) unsigned*)(gPtr[c]),
            (__attribute__((address_space(3))) unsigned*)(&L[0][lOfs[c]]), 16, 0, 0);
    __syncthreads();

    int cur = 0;
    for (int k0 = 32; k0 < K; k0 += 32) {
#pragma unroll
        for (int c = 0; c < 4; ++c)
            __builtin_amdgcn_global_load_lds(
                (const __attribute__((address_space(1))) unsigned*)(gPtr[c] + k0),
                (__attribute__((address_space(3))) unsigned*)(&L[cur ^ 1][lOfs[c]]), 16, 0, 0);
        {
            bf16x8 af[4], bg[4];
#pragma unroll
            for (int m = 0; m < 4; ++m)
                af[m] = *reinterpret_cast<const bf16x8*>(&L[cur][afr + m * 512]);
#pragma unroll
            for (int n = 0; n < 4; ++n)
                bg[n] = *reinterpret_cast<const bf16x8*>(&L[cur][bfr + n * 512]);
#pragma unroll
            for (int m = 0; m < 4; ++m)
#pragma unroll
                for (int n = 0; n < 4; ++n)
                    acc[m][n] = __builtin_amdgcn_mfma_f32_16x16x32_bf16(af[m], bg[n], acc[m][n], 0, 0, 0);
        }
        __syncthreads();
        cur ^= 1;
    }
    {
        bf16x8 af[4], bg[4];
#pragma unroll
        for (int m = 0; m < 4; ++m)
            af[m] = *reinterpret_cast<const bf16x8*>(&L[cur][afr + m * 512]);
#pragma unroll
        for (int n = 0; n < 4; ++n)
            bg[n] = *reinterpret_cast<const bf16x8*>(&L[cur][bfr + n * 512]);
#pragma unroll
        for (int m = 0; m < 4; ++m)
#pragma unroll
            for (int n = 0; n < 4; ++n)
                acc[m][n] = __builtin_amdgcn_mfma_f32_16x16x32_bf16(af[m], bg[n], acc[m][n], 0, 0, 0);
    }

    const int crow = row0 + wm * 64 + (lane >> 4) * 4;
    const int ccol = col0 + wn * 64 + (lane & 15);
#pragma unroll
    for (int m = 0; m < 4; ++m) {
#pragma unroll
        for (int j = 0; j < 4; ++j) {
            int r = crow + m * 16 + j;
            if (r < M) {
#pragma unroll
                for (int n = 0; n < 4; ++n)
                    Cb[(size_t)r * N + ccol + n * 16] = f2bf(acc[m][n][j]);
            }
        }
    }

    float as_c[4], ad_c[4];
#pragma unroll
    for (int n = 0; n < 4; ++n) {
        int cl = wn * 64 + n * 16 + (lane & 15);
        as_c[n] = asrc[blockIdx.y * 128 + cl];
        ad_c[n] = adst[blockIdx.y * 128 + cl];
    }
#pragma unroll
    for (int m = 0; m < 4; ++m) {
#pragma unroll
        for (int j = 0; j < 4; ++j) {
            float ps = acc[m][0][j] * as_c[0] + acc[m][1][j] * as_c[1] +
                       acc[m][2][j] * as_c[2] + acc[m][3][j] * as_c[3];
            float pd = acc[m][0][j] * ad_c[0] + acc[m][1][j] * ad_c[1] +
                       acc[m][2][j] * ad_c[2] + acc[m][3][j] * ad_c[3];
#pragma unroll
            for (int o = 1; o < 16; o <<= 1) {
                ps += __shfl_xor(ps, o);
                pd += __shfl_xor(pd, o);
            }
            if ((lane & 15) == 0) {
                int rl = wm * 64 + (lane >> 4) * 4 + m * 16 + j;
                sles[wn][rl] = ps;
                sled[wn][rl] = pd;
            }
        }
    }
    __syncthreads();
    if (tid < 128) {
        int r = row0 + tid;
        if (r < M) {
            es[(size_t)r * H + blockIdx.y] = sles[0][tid] + sles[1][tid];
            ed[(size_t)r * H + blockIdx.y] = sled[0][tid] + sled[1][tid];
        }
    }
}

// ---- wave-per-node softmax aggregation + bias + BN + ReLU ----
template <int H, bool BF16OUT>
__global__ __launch_bounds__(64) void k_agg(
    const ushort* __restrict__ xpb, const float* __restrict__ es, const float* __restrict__ ed,
    const int* __restrict__ row_ptr, const int* __restrict__ colb,
    const float* __restrict__ bias, const float* __restrict__ gg, const float* __restrict__ be,
    const float* __restrict__ mu, const float* __restrict__ var, void* __restrict__ outv) {
    constexpr int HC = H * 128;
    constexpr int CPT = HC / 64;  // 8 (H=4) or 2 (H=1)
    constexpr int CHUNK = 128;
    constexpr int GS = (H == 4) ? 16 : 64;
    __shared__ int s_src[CHUNK];
    __shared__ float s_w[CHUNK][H];
    const int n = blockIdx.x;
    const int lane = threadIdx.x;
    const int g = (H == 4) ? (lane >> 4) : 0;
    const int gl = (H == 4) ? (lane & 15) : lane;
    const int beg = row_ptr[n], end = row_ptr[n + 1];
    const int cnt = end - beg;

    float edn[H];
#pragma unroll
    for (int h = 0; h < H; ++h) edn[h] = ed[n * H + h];

    float acc[CPT];
#pragma unroll
    for (int j = 0; j < CPT; ++j) acc[j] = 0.f;
    float m_run = -INFINITY, s_run = 0.f;
    const int ch0 = lane * CPT;
    const ushort* xb = xpb + ch0;

    for (int cbeg = 0; cbeg < cnt; cbeg += CHUNK) {
        const int cc = min(cnt - cbeg, CHUNK);
        for (int i = lane; i < cc; i += 64) {
            int src = colb[beg + cbeg + i];
            s_src[i] = src;
            if (H == 4) {
                float4 e4 = *reinterpret_cast<const float4*>(&es[src * 4]);
                float4 o;
                o.x = e4.x + edn[0]; o.x = (o.x > 0.f) ? o.x : NEG_SLOPE * o.x;
                o.y = e4.y + edn[1]; o.y = (o.y > 0.f) ? o.y : NEG_SLOPE * o.y;
                o.z = e4.z + edn[2]; o.z = (o.z > 0.f) ? o.z : NEG_SLOPE * o.z;
                o.w = e4.w + edn[3]; o.w = (o.w > 0.f) ? o.w : NEG_SLOPE * o.w;
                *reinterpret_cast<float4*>(&s_w[i][0]) = o;
            } else {
                float e = es[src] + edn[0];
                s_w[i][0] = (e > 0.f) ? e : NEG_SLOPE * e;
            }
        }
        __syncthreads();
        float cm = -INFINITY;
        for (int i = gl; i < cc; i += GS) cm = fmaxf(cm, s_w[i][g]);
#pragma unroll
        for (int o = GS >> 1; o; o >>= 1) cm = fmaxf(cm, __shfl_xor(cm, o));
        const float m_new = fmaxf(m_run, cm);
        const float scale = __expf(m_run - m_new);  // first chunk: exp(-inf)=0
        float sl = 0.f;
        for (int i = gl; i < cc; i += GS) {
            float w = __expf(s_w[i][g] - m_new);
            s_w[i][g] = w;
            sl += w;
        }
#pragma unroll
        for (int o = GS >> 1; o; o >>= 1) sl += __shfl_xor(sl, o);
        s_run = s_run * scale + sl;
        m_run = m_new;
#pragma unroll
        for (int j = 0; j < CPT; ++j) acc[j] *= scale;
        __syncthreads();
        for (int e = 0; e < cc; e += 4) {
            float w0 = s_w[e][g];
            int   p0 = s_src[e];
            float w1 = 0.f; int p1 = n;
            float w2 = 0.f; int p2 = n;
            float w3 = 0.f; int p3 = n;
            if (e + 1 < cc) { w1 = s_w[e + 1][g]; p1 = s_src[e + 1]; }
            if (e + 2 < cc) { w2 = s_w[e + 2][g]; p2 = s_src[e + 2]; }
            if (e + 3 < cc) { w3 = s_w[e + 3][g]; p3 = s_src[e + 3]; }
            if (CPT == 8) {
                u16x8 v0 = *reinterpret_cast<const u16x8*>(xb + (size_t)p0 * HC);
                u16x8 v1 = *reinterpret_cast<const u16x8*>(xb + (size_t)p1 * HC);
                u16x8 v2 = *reinterpret_cast<const u16x8*>(xb + (size_t)p2 * HC);
                u16x8 v3 = *reinterpret_cast<const u16x8*>(xb + (size_t)p3 * HC);
#pragma unroll
                for (int j = 0; j < CPT; ++j) {
                    float a = acc[j];
                    a = fmaf(w0, bf2f(v0[j]), a);
                    a = fmaf(w1, bf2f(v1[j]), a);
                    a = fmaf(w2, bf2f(v2[j]), a);
                    a = fmaf(w3, bf2f(v3[j]), a);
                    acc[j] = a;
                }
            } else {
                u16x2 v0 = *reinterpret_cast<const u16x2*>(xb + (size_t)p0 * HC);
                u16x2 v1 = *reinterpret_cast<const u16x2*>(xb + (size_t)p1 * HC);
                u16x2 v2 = *reinterpret_cast<const u16x2*>(xb + (size_t)p2 * HC);
                u16x2 v3 = *reinterpret_cast<const u16x2*>(xb + (size_t)p3 * HC);
#pragma unroll
                for (int j = 0; j < CPT; ++j) {
                    float a = acc[j];
                    a = fmaf(w0, bf2f(v0[j]), a);
                    a = fmaf(w1, bf2f(v1[j]), a);
                    a = fmaf(w2, bf2f(v2[j]), a);
                    a = fmaf(w3, bf2f(v3[j]), a);
                    acc[j] = a;
                }
            }
        }
        __syncthreads();
    }

    const float inv = 1.f / (s_run + 1e-16f);
    float vals[CPT];
#pragma unroll
    for (int j = 0; j < CPT; ++j) {
        int ch = ch0 + j;
        float val = acc[j] * inv + bias[ch];
        val = (val - mu[ch]) * (gg[ch] * rsqrtf(var[ch] + BN_EPS)) + be[ch];
        vals[j] = fmaxf(val, 0.f);
    }
    if (BF16OUT) {
        if (CPT == 8) {
            u16x8 o;
#pragma unroll
            for (int j = 0; j < CPT; ++j) o[j] = f2bf(vals[j]);
            *reinterpret_cast<u16x8*>((ushort*)outv + (size_t)n * HC + ch0) = o;
        } else {
            u16x2 o;
#pragma unroll
            for (int j = 0; j < CPT; ++j) o[j] = f2bf(vals[j]);
            *reinterpret_cast<u16x2*>((ushort*)outv + (size_t)n * HC + ch0) = o;
        }
    } else {
        float2 o = make_float2(vals[0], vals[1 % CPT]);
        *reinterpret_cast<float2*>((float*)outv + (size_t)n * HC + ch0) = o;
    }
}

// ---------------- classifier: LDS-staged, 16 nodes / 256-thread block ----------------
#define CLS_NB 16
__global__ __launch_bounds__(256) void k_cls(const float* __restrict__ Eg,
                                             const float* __restrict__ Wc1,
                                             const float* __restrict__ bc1,
                                             const float* __restrict__ Wc2,
                                             const float* __restrict__ bc2,
                                             float* __restrict__ P) {
    __shared__ float Ws[128 * 64];
    __shared__ float W2s[64 * 10 + 16];
    __shared__ float b1s[64];
    __shared__ float e_sh[CLS_NB][128];
    __shared__ float h_sh[CLS_NB][64];
    __shared__ float l_sh[CLS_NB][10];
    const int t = threadIdx.x;
    const int n0 = blockIdx.x * CLS_NB;

    for (int i = t; i < 2048; i += 256)
        reinterpret_cast<float4*>(Ws)[i] = reinterpret_cast<const float4*>(Wc1)[i];
    for (int i = t; i < 640; i += 256) W2s[i] = Wc2[i];
    if (t < 64) b1s[t] = bc1[t];
    if (t >= 64 && t < 74) W2s[640 + t - 64] = bc2[t - 64];
    for (int i = t; i < CLS_NB * 32; i += 256) {
        int node = i >> 5, qq = i & 31;
        reinterpret_cast<float4*>(&e_sh[node][0])[qq] =
            reinterpret_cast<const float4*>(&Eg[(size_t)(n0 + node) * 128])[qq];
    }
    __syncthreads();

    {
        const int c = t & 63, ng = t >> 6;
        float acc0 = b1s[c], acc1 = b1s[c], acc2 = b1s[c], acc3 = b1s[c];
        for (int k = 0; k < 128; ++k) {
            float w = Ws[k * 64 + c];
            acc0 = fmaf(e_sh[ng * 4 + 0][k], w, acc0);
            acc1 = fmaf(e_sh[ng * 4 + 1][k], w, acc1);
            acc2 = fmaf(e_sh[ng * 4 + 2][k], w, acc2);
            acc3 = fmaf(e_sh[ng * 4 + 3][k], w, acc3);
        }
        h_sh[ng * 4 + 0][c] = fmaxf(acc0, 0.f);
        h_sh[ng * 4 + 1][c] = fmaxf(acc1, 0.f);
        h_sh[ng * 4 + 2][c] = fmaxf(acc2, 0.f);
        h_sh[ng * 4 + 3][c] = fmaxf(acc3, 0.f);
    }
    __syncthreads();
    if (t < CLS_NB * 10) {
        int node = t / 10, c = t - node * 10;
        float acc = W2s[640 + c];
        for (int k = 0; k < 64; ++k) acc = fmaf(h_sh[node][k], W2s[k * 10 + c], acc);
        l_sh[node][c] = acc;
    }
    __syncthreads();
    if (t < CLS_NB) {
        float mx = l_sh[t][0];
        for (int j = 1; j < 10; ++j) mx = fmaxf(mx, l_sh[t][j]);
        float s = 0.f;
        float ex[10];
        for (int j = 0; j < 10; ++j) { ex[j] = __expf(l_sh[t][j] - mx); s += ex[j]; }
        float inv = 1.f / s;
        for (int j = 0; j < 10; ++j) l_sh[t][j] = ex[j] * inv;
    }
    __syncthreads();
    if (t < CLS_NB * 10) {
        int node = t / 10, c = t - node * 10;
        P[(size_t)(n0 + node) * 10 + c] = l_sh[node][c];
    }
}

extern "C" void kernel_launch(void* const* d_in, const int* in_sizes, int n_in,
                              void* d_out, int out_size, void* d_ws, size_t ws_size,
                              hipStream_t stream) {
    const float* x     = (const float*)d_in[0];
    const int*   ei    = (const int*)d_in[1];
    const float* W1    = (const float*)d_in[2];
    const float* asrc1 = (const float*)d_in[3];
    const float* adst1 = (const float*)d_in[4];
    const float* b1    = (const float*)d_in[5];
    const float* gg1   = (const float*)d_in[6];
    const float* be1   = (const float*)d_in[7];
    const float* mu1   = (const float*)d_in[8];
    const float* v1    = (const float*)d_in[9];
    const float* W2    = (const float*)d_in[10];
    const float* asrc2 = (const float*)d_in[11];
    const float* adst2 = (const float*)d_in[12];
    const float* b2    = (const float*)d_in[13];
    const float* gg2   = (const float*)d_in[14];
    const float* be2   = (const float*)d_in[15];
    const float* mu2   = (const float*)d_in[16];
    const float* v2    = (const float*)d_in[17];
    const float* W3    = (const float*)d_in[18];
    const float* asrc3 = (const float*)d_in[19];
    const float* adst3 = (const float*)d_in[20];
    const float* b3    = (const float*)d_in[21];
    const float* gg3   = (const float*)d_in[22];
    const float* be3   = (const float*)d_in[23];
    const float* mu3   = (const float*)d_in[24];
    const float* v3    = (const float*)d_in[25];
    const float* Wc1   = (const float*)d_in[26];
    const float* bc1   = (const float*)d_in[27];
    const float* Wc2   = (const float*)d_in[28];
    const float* bc2   = (const float*)d_in[29];

    // ---- workspace layout (~107 MB) ----
    ushort* xpb  = (ushort*)d_ws;                      // bf16 xp, N*512
    ushort* hh   = xpb + (size_t)N_NODES * 512;        // bf16 GEMM input, N*512
    ushort* wt1  = hh + (size_t)N_NODES * 512;         // 512*256
    ushort* wt2  = wt1 + 512 * 256;                    // 512*512
    ushort* wt3  = wt2 + 512 * 512;                    // 128*512
    float*  es   = (float*)(wt3 + 128 * 512);
    float*  ed   = es + (size_t)N_NODES * 4;
    int* cnt     = (int*)(ed + (size_t)N_NODES * 4);
    int* off     = cnt + N_NODES;
    int* row_ptr = off + N_NODES;
    int* colb    = row_ptr + N_NODES + 4;
    int* incl    = colb + N_EDGES + N_NODES;
    int* partials = incl + N_NODES;

    float* Egnn = (float*)d_out;
    float* P    = Egnn + (size_t)N_NODES * 128;

    // ---- CSR build (cnt+off zeroed by one memset; +1 folded into scan1/scatter) ----
    hipMemsetAsync(cnt, 0, 2 * (size_t)N_NODES * sizeof(int), stream);
    k_count<<<(N_EDGES + 255) / 256, 256, 0, stream>>>(ei, cnt);
    k_scan1<<<SCAN_NB, 256, 0, stream>>>(cnt, incl, partials);
    k_scan3self<<<(N_NODES + 255) / 256, 256, 0, stream>>>(incl, partials, row_ptr, colb);
    k_scatter<<<(N_EDGES + 255) / 256, 256, 0, stream>>>(ei, row_ptr, off, colb);

    // ---- fused weight transpose-converts + x convert ----
    {
        int total = PREP_S1 + PREP_S2 + PREP_S3 + PREP_S4;
        k_prep<<<(total + 255) / 256, 256, 0, stream>>>(W1, W2, W3, x, wt1, wt2, wt3, hh);
    }

    const int mt = (N_NODES + 127) / 128;  // 391
    const int nwg256 = mt * 2;             // 782 (column-block fastest)

    // ---- layer 1: 256 -> 4x128 ----
    k_gemm256<<<nwg256, 512, 0, stream>>>(hh, wt1, xpb, asrc1, adst1, es, ed,
                                          N_NODES, 256);
    k_agg<4, true><<<N_NODES, 64, 0, stream>>>(xpb, es, ed, row_ptr, colb,
                                               b1, gg1, be1, mu1, v1, hh);
    // ---- layer 2: 512 -> 4x128 ----
    k_gemm256<<<nwg256, 512, 0, stream>>>(hh, wt2, xpb, asrc2, adst2, es, ed,
                                          N_NODES, 512);
    k_agg<4, true><<<N_NODES, 64, 0, stream>>>(xpb, es, ed, row_ptr, colb,
                                               b2, gg2, be2, mu2, v2, hh);
    // ---- layer 3: 512 -> 1x128 ----
    {
        dim3 grid(mt, 1);
        k_gemm_bf16<<<grid, 256, 0, stream>>>(hh, wt3, xpb, asrc3, adst3, es, ed,
                                              N_NODES, 512, 128);
    }
    k_agg<1, false><<<N_NODES, 64, 0, stream>>>(xpb, es, ed, row_ptr, colb,
                                                b3, gg3, be3, mu3, v3, Egnn);
    // ---- classifier ----
    k_cls<<<(N_NODES + CLS_NB - 1) / CLS_NB, 256, 0, stream>>>(Egnn, Wc1, bc1, Wc2, bc2, P);
}